// Round 2
// baseline (2699.103 us; speedup 1.0000x reference)
//
#include <hip/hip_runtime.h>
#include <math.h>

typedef unsigned short u16t;
typedef unsigned int   u32t;
using short8 = __attribute__((ext_vector_type(8))) short;
using f32x4  = __attribute__((ext_vector_type(4))) float;

// ---------------- workspace layout (u16 elements) ----------------
#define SZ_S   67108864LL   // 8192*8192
#define SZ_F   16777216LL   // 2048*8192
#define SZ_G   8388608LL    // 1024*8192
#define OFF_S0  0LL
#define OFF_S1  67108864LL
#define OFF_XT  134217728LL  // x^T        (2048 x 8192) rows b*128 + dcat
#define OFF_X10 150994944LL  // (S0 x)^T
#define OFF_Z0  167772160LL  // (S0 S0 x)^T
#define OFF_X11 184549376LL  // (S1 x)^T
#define OFF_Z1  201326592LL  // (S1 S1 x)^T
#define OFF_RUT 218103808LL  // sigmoid(gconv1)^T (2048 x 8192) rows b*128 + o
#define OFF_YT  234881024LL  // (r*states)^T (1024 x 8192) rows b*64 + d
#define OFF_Y10 243269632LL
#define OFF_ZY0 251658240LL
#define OFF_Y11 260046848LL
#define OFF_ZY1 268435456LL
#define OFF_CT  276824064LL  // tanh(gconv2)^T (1024 x 8192)
#define OFF_WRU 285212672LL  // folded W_ru^T (128 x 640)
#define OFF_WC  285294592LL  // folded W_c^T  (64 x 640, padded to 128 rows)

__device__ __forceinline__ u16t f2b(float f) {   // fp32 -> bf16 RNE
  u32t x = __float_as_uint(f);
  x += 0x7fffu + ((x >> 16) & 1u);
  return (u16t)(x >> 16);
}
__device__ __forceinline__ float b2f(u16t h) {
  return __uint_as_float(((u32t)h) << 16);
}
__device__ __forceinline__ void async16(const u16t* g, u16t* l) {
  __builtin_amdgcn_global_load_lds((const __attribute__((address_space(1))) void*)g,
                                   (__attribute__((address_space(3))) void*)l, 16, 0, 0);
}

// ---------------- S fp32 -> bf16 (both supports, contiguous) ----------------
__global__ void convert_s(const float* __restrict__ S, u16t* __restrict__ ws) {
  const long long tid = (long long)blockIdx.x * 256 + threadIdx.x; // 16777216 threads
  const float4* p = (const float4*)S;
  const float4 a = p[tid * 2];
  const float4 b = p[tid * 2 + 1];
  short8 o;
  o[0] = (short)f2b(a.x); o[1] = (short)f2b(a.y);
  o[2] = (short)f2b(a.z); o[3] = (short)f2b(a.w);
  o[4] = (short)f2b(b.x); o[5] = (short)f2b(b.y);
  o[6] = (short)f2b(b.z); o[7] = (short)f2b(b.w);
  *(short8*)&ws[OFF_S0 + tid * 8] = o;
}

// ---------------- build x^T (2048 x 8192) bf16 from inputs/states ----------------
__global__ void build_xt(const float* __restrict__ inputs,
                         const float* __restrict__ states,
                         u16t* __restrict__ ws) {
  __shared__ float tile[64][65];
  const int n0 = blockIdx.x * 64;
  const int half = blockIdx.y;   // 0: inputs, 1: states
  const int b = blockIdx.z;
  const float* src = half ? states : inputs;
  const int t = threadIdx.x;
  const int d = t & 63, nl = t >> 6;
#pragma unroll
  for (int p = 0; p < 16; ++p) {
    const int n = p * 4 + nl;
    tile[d][n] = src[((long long)b * 8192 + n0 + n) * 64 + d];  // coalesced in d
  }
  __syncthreads();
  const int nn = t & 63, cl = t >> 6;
#pragma unroll
  for (int p = 0; p < 16; ++p) {
    const int c = p * 4 + cl;
    ws[OFF_XT + (long long)(b * 128 + half * 64 + c) * 8192 + n0 + nn] = f2b(tile[c][nn]);
  }
}

// ---------------- fold + transpose weights to bf16 ----------------
__global__ void prep_w(const float* __restrict__ Wru, const float* __restrict__ Wc,
                       u16t* __restrict__ ws) {
  const int t = blockIdx.x * 256 + threadIdx.x; // 122880 total
  if (t < 81920) {
    const int o = t / 640, f = t - o * 640;
    const int feat = f >> 7, dc = f & 127;
    float v;
    switch (feat) {
      case 0:  v = Wru[dc * 128 + o] - Wru[(256 + dc) * 128 + o] - Wru[(512 + dc) * 128 + o]; break;
      case 1:  v = Wru[(128 + dc) * 128 + o]; break;
      case 2:  v = 2.f * Wru[(256 + dc) * 128 + o]; break;
      case 3:  v = Wru[(384 + dc) * 128 + o]; break;
      default: v = 2.f * Wru[(512 + dc) * 128 + o]; break;
    }
    ws[OFF_WRU + t] = f2b(v);
  } else {
    const int t2 = t - 81920;
    const int o = t2 / 640, f = t2 - o * 640;
    const int feat = f >> 7, dc = f & 127;
    float v;
    switch (feat) {
      case 0:  v = Wc[dc * 64 + o] - Wc[(256 + dc) * 64 + o] - Wc[(512 + dc) * 64 + o]; break;
      case 1:  v = Wc[(128 + dc) * 64 + o]; break;
      case 2:  v = 2.f * Wc[(256 + dc) * 64 + o]; break;
      case 3:  v = Wc[(384 + dc) * 64 + o]; break;
      default: v = 2.f * Wc[(512 + dc) * 64 + o]; break;
    }
    ws[OFF_WC + t2] = f2b(v);
  }
}

// ---------------- big GEMM, 256x256 tile, BK=32, ring-4, read-ahead ------------
// Out[r][m] = sum_k A[r][k] * S[m][k];  A: (R x 8192), S: (8192 x 8192), bf16.
// 512 threads = 8 waves (2M x 4N), per-wave C = 128x64.
// Ring of 4 LDS buffers (32 KiB each = A 16K + B 16K). 2 phases per K-tile,
// 16 MFMA per phase. Fragments for phase p are ds_read during phase p-1, so
// the LDS drain overlaps the previous MFMA cluster (compiler inserts counted
// lgkmcnt). One counted vmcnt(4) per tile, never 0.
// Ledger: at end of tile T only {A(T+3),B(T+3)} (4 instr) remain in flight ->
// buf[T+2] landed -> invariant "on entry to tile T: buf[T+1] valid".
// Overwrite: STAGE_A(T+3) hits buf[(T-1)&3]; its last reads (ph0(T-1)) were
// lgkm-drained before ph1(T-1)'s MFMA + trailing barrier. Safe.
#define STAGE_A(kt, dst)                                                        \
  { const long long kw = (long long)(((kt) & 255) * 32);                        \
    async16(gA + (long long)srow2 * 8192 + kw + sgc8, (dst) + sldo);            \
    async16(gA + (long long)(srow2 + 128) * 8192 + kw + sgc8, (dst) + 4096 + sldo); }
#define STAGE_B(kt, dst)                                                        \
  { const long long kw = (long long)(((kt) & 255) * 32);                        \
    async16(gB + (long long)srow2 * 8192 + kw + sgc8, (dst) + 8192 + sldo);     \
    async16(gB + (long long)(srow2 + 128) * 8192 + kw + sgc8, (dst) + 12288 + sldo); }

__global__ __launch_bounds__(512, 2) void gemm256(const u16t* __restrict__ Aa,
                                                  const u16t* __restrict__ Sa,
                                                  u16t* __restrict__ Oa,
                                                  const u16t* __restrict__ Ab,
                                                  const u16t* __restrict__ Sb,
                                                  u16t* __restrict__ Ob) {
  __shared__ __align__(16) u16t lds[4][16384];  // [buf][A:0..8191 | B:8192..16383]
  const int t = threadIdx.x;
  const int l = t & 63;
  const int w = t >> 6;                 // 0..7
  // bijective XCD swizzle within the z-slice (nflat % 8 == 0 always here)
  const int id = blockIdx.y * 32 + blockIdx.x;
  const int cpx = (gridDim.y * 32) >> 3;
  const int swz = (id & 7) * cpx + (id >> 3);
  const int bx = swz & 31, by = swz >> 5;
  const long long m0 = (long long)bx * 256;
  const long long r0 = (long long)by * 256;
  const u16t* A = blockIdx.z ? Ab : Aa;
  const u16t* S = blockIdx.z ? Sb : Sa;
  u16t* Out = blockIdx.z ? Ob : Oa;
  const u16t* gA = A + r0 * 8192;
  const u16t* gB = S + m0 * 8192;

  const int wr = (w >> 2) * 128;        // A-row group: 0 or 128
  const int wc = (w & 3) * 64;          // B-row group: 0,64,128,192
  const int lm = l & 15, lq = l >> 4;

  // staging: thread t, instr i -> row i*128 + (t>>2), k-chunk (t&3)^((t>>3)&3)
  const int srow2 = t >> 2;
  const int sgc8 = ((t & 3) ^ ((t >> 3) & 3)) * 8;
  const int sldo = t * 8;

  // frag reads: row = base + lm, chunk = lq ^ ((row>>1)&3) = lq ^ ((lm>>1)&3)
  // (all bases are multiples of 16). 2 lanes per bank-quad per 16-lane group.
  const int ch8 = (lq ^ ((lm >> 1) & 3)) * 8;
  const int aoff = (wr + lm) * 32 + ch8;
  const int boff0 = 8192 + (wc + lm) * 32 + ch8;   // B cols 0,1 (rows wc+0..31)
  const int boff1 = boff0 + 1024;                   // B cols 2,3 (rows wc+32..63)

  f32x4 acc[8][4];
#pragma unroll
  for (int i = 0; i < 8; ++i)
#pragma unroll
    for (int j = 0; j < 4; ++j) acc[i][j] = f32x4{0.f, 0.f, 0.f, 0.f};

  // prologue: stage tiles 0,1,2; land 0 and 1; read ph0(0) frags
  STAGE_A(0, &lds[0][0]); STAGE_B(0, &lds[0][0]);
  STAGE_A(1, &lds[1][0]); STAGE_B(1, &lds[1][0]);
  STAGE_A(2, &lds[2][0]); STAGE_B(2, &lds[2][0]);
  asm volatile("s_waitcnt vmcnt(4)" ::: "memory");
  __builtin_amdgcn_s_barrier();

  short8 fa[8], fb[2], ga[8], gb[2];
  {
    const u16t* b0 = &lds[0][0];
#pragma unroll
    for (int mi = 0; mi < 8; ++mi) fa[mi] = *(const short8*)&b0[aoff + mi * 512];
#pragma unroll
    for (int j = 0; j < 2; ++j) fb[j] = *(const short8*)&b0[boff0 + j * 512];
  }

#pragma unroll 1
  for (int T = 0; T < 256; ++T) {
    const u16t* bT  = &lds[T & 3][0];
    const u16t* bT1 = &lds[(T + 1) & 3][0];
    u16t* sD = &lds[(T + 3) & 3][0];
    // ---- phase 0: MFMA(fa,fb -> cols 0,1); read ga/gb (cols 2,3 of tile T)
    STAGE_A(T + 3, sD);
#pragma unroll
    for (int mi = 0; mi < 8; ++mi) ga[mi] = *(const short8*)&bT[aoff + mi * 512];
#pragma unroll
    for (int j = 0; j < 2; ++j) gb[j] = *(const short8*)&bT[boff1 + j * 512];
    __builtin_amdgcn_s_barrier();
    __builtin_amdgcn_s_setprio(1);
#pragma unroll
    for (int mi = 0; mi < 8; ++mi) {
      acc[mi][0] = __builtin_amdgcn_mfma_f32_16x16x32_bf16(fa[mi], fb[0], acc[mi][0], 0, 0, 0);
      acc[mi][1] = __builtin_amdgcn_mfma_f32_16x16x32_bf16(fa[mi], fb[1], acc[mi][1], 0, 0, 0);
    }
    __builtin_amdgcn_s_setprio(0);
    __builtin_amdgcn_s_barrier();
    // ---- phase 1: MFMA(ga,gb -> cols 2,3); read fa/fb (cols 0,1 of tile T+1)
    STAGE_B(T + 3, sD);
#pragma unroll
    for (int mi = 0; mi < 8; ++mi) fa[mi] = *(const short8*)&bT1[aoff + mi * 512];
#pragma unroll
    for (int j = 0; j < 2; ++j) fb[j] = *(const short8*)&bT1[boff0 + j * 512];
    __builtin_amdgcn_s_barrier();
    __builtin_amdgcn_s_setprio(1);
#pragma unroll
    for (int mi = 0; mi < 8; ++mi) {
      acc[mi][2] = __builtin_amdgcn_mfma_f32_16x16x32_bf16(ga[mi], gb[0], acc[mi][2], 0, 0, 0);
      acc[mi][3] = __builtin_amdgcn_mfma_f32_16x16x32_bf16(ga[mi], gb[1], acc[mi][3], 0, 0, 0);
    }
    __builtin_amdgcn_s_setprio(0);
    asm volatile("s_waitcnt vmcnt(4)" ::: "memory");
    __builtin_amdgcn_s_barrier();
  }

  // C/D layout: col = lane&15, row = (lane>>4)*4 + reg  [m89-verified]
#pragma unroll
  for (int mi = 0; mi < 8; ++mi)
#pragma unroll
    for (int nj = 0; nj < 4; ++nj)
#pragma unroll
      for (int rr = 0; rr < 4; ++rr) {
        const long long r = r0 + wr + mi * 16 + lq * 4 + rr;
        const long long c = m0 + wc + nj * 16 + lm;
        Out[r * 8192 + c] = f2b(acc[mi][nj][rr]);
      }
}

// ---------------- projection GEMM: K=640 over 10 chunk sources ----------------
__global__ __launch_bounds__(256, 2) void proj(const u16t* __restrict__ ws_c,
                                               u16t* __restrict__ ws_m,
                                               const float* __restrict__ bias,
                                               const int variant) {
  __shared__ __align__(16) u16t As[128 * 64];
  __shared__ __align__(16) u16t Bt[128 * 72];  // [n][f], padded stride 72
  const long long FOFF[5] = {OFF_XT, OFF_X10, OFF_Z0, OFF_X11, OFF_Z1};
  const long long GOFF[5] = {OFF_YT, OFF_Y10, OFF_ZY0, OFF_Y11, OFF_ZY1};
  const int t = threadIdx.x;
  const int l = t & 63;
  const int w = t >> 6;
  const int n0 = blockIdx.x * 128;
  const int b = blockIdx.y;
  const u16t* Wt = ws_c + (variant ? OFF_WC : OFF_WRU);

  const int srow = t >> 3;
  const int schunk = ((t & 7) ^ (srow & 7)) * 8;
  const int wr = (w >> 1) * 64, wm = (w & 1) * 64;
  const int lm = l & 15, lq = l >> 4;

  f32x4 acc[4][4];
#pragma unroll
  for (int i = 0; i < 4; ++i)
#pragma unroll
    for (int j = 0; j < 4; ++j) acc[i][j] = f32x4{0.f, 0.f, 0.f, 0.f};

  for (int q = 0; q < 10; ++q) {
    const int feat = q >> 1, half = q & 1;
    long long brow;
    if (variant == 0)
      brow = FOFF[feat] + (long long)(b * 128 + half * 64) * 8192;
    else
      brow = half ? (GOFF[feat] + (long long)(b * 64) * 8192)
                  : (FOFF[feat] + (long long)(b * 128) * 8192);
#pragma unroll
    for (int i = 0; i < 4; ++i)
      async16(Wt + (i * 32 + srow) * 640 + q * 64 + schunk, &As[i * 2048 + t * 8]);
    const int fr = t >> 4;
    const int noff = (t & 15) * 8;
#pragma unroll
    for (int p = 0; p < 4; ++p) {
      const int f = p * 16 + fr;
      short8 v = *(const short8*)&ws_c[brow + (long long)f * 8192 + n0 + noff];
#pragma unroll
      for (int e = 0; e < 8; ++e) Bt[(noff + e) * 72 + f] = (u16t)v[e];
    }
    __syncthreads();
#pragma unroll
    for (int s = 0; s < 2; ++s) {
      short8 af[4], bf[4];
      const int ch = s * 4 + lq;
#pragma unroll
      for (int i = 0; i < 4; ++i) {
        const int mr = wr + i * 16 + lm;
        const int nr = wm + i * 16 + lm;
        af[i] = *(const short8*)&As[mr * 64 + ((ch ^ (mr & 7)) * 8)];
        bf[i] = *(const short8*)&Bt[nr * 72 + s * 32 + lq * 8];
      }
#pragma unroll
      for (int i = 0; i < 4; ++i)
#pragma unroll
        for (int j = 0; j < 4; ++j)
          acc[i][j] = __builtin_amdgcn_mfma_f32_16x16x32_bf16(af[i], bf[j], acc[i][j], 0, 0, 0);
    }
    __syncthreads();
  }

  if (variant == 0) {
#pragma unroll
    for (int i = 0; i < 4; ++i)
#pragma unroll
      for (int j = 0; j < 4; ++j)
#pragma unroll
        for (int rr = 0; rr < 4; ++rr) {
          const int o = wr + i * 16 + lq * 4 + rr;
          const int c = n0 + wm + j * 16 + lm;
          const float x = acc[i][j][rr] + bias[o];
          const float sg = 1.f / (1.f + __expf(-x));
          ws_m[OFF_RUT + (long long)(b * 128 + o) * 8192 + c] = f2b(sg);
        }
  } else if (wr == 0) {
#pragma unroll
    for (int i = 0; i < 4; ++i)
#pragma unroll
      for (int j = 0; j < 4; ++j)
#pragma unroll
        for (int rr = 0; rr < 4; ++rr) {
          const int o = i * 16 + lq * 4 + rr;  // < 64
          const int c = n0 + wm + j * 16 + lm;
          const float x = acc[i][j][rr] + bias[o];
          ws_m[OFF_CT + (long long)(b * 64 + o) * 8192 + c] = f2b(tanhf(x));
        }
  }
}

// ---------------- Y^T = (r * states)^T, bf16 ----------------
__global__ void build_y(u16t* __restrict__ ws) {
  const long long tid = (long long)blockIdx.x * 256 + threadIdx.x; // 1048576
  const int ry = (int)(tid >> 10);
  const int nc = ((int)tid & 1023) * 8;
  const int b = ry >> 6, d = ry & 63;
  const short8 r8 = *(const short8*)&ws[OFF_RUT + (long long)(b * 128 + d) * 8192 + nc];
  const short8 s8 = *(const short8*)&ws[OFF_XT + (long long)(b * 128 + 64 + d) * 8192 + nc];
  short8 o;
#pragma unroll
  for (int e = 0; e < 8; ++e) o[e] = (short)f2b(b2f((u16t)r8[e]) * b2f((u16t)s8[e]));
  *(short8*)&ws[OFF_YT + (long long)ry * 8192 + nc] = o;
}

// ---------------- final: out = u*states + (1-u)*c, two copies ----------------
__global__ void final_out(const u16t* __restrict__ ws,
                          const float* __restrict__ states,
                          float* __restrict__ out) {
  __shared__ float lu[64][65];
  __shared__ float lc[64][65];
  const int t = threadIdx.x;
  const int b = blockIdx.y;
  const int n0 = blockIdx.x * 64;
  const int dd = t >> 3, noff = (t & 7) * 8;
#pragma unroll
  for (int p = 0; p < 2; ++p) {
    const int d = p * 32 + dd;
    short8 u8 = *(const short8*)&ws[OFF_RUT + (long long)(b * 128 + 64 + d) * 8192 + n0 + noff];
    short8 c8 = *(const short8*)&ws[OFF_CT + (long long)(b * 64 + d) * 8192 + n0 + noff];
#pragma unroll
    for (int e = 0; e < 8; ++e) {
      lu[d][noff + e] = b2f((u16t)u8[e]);
      lc[d][noff + e] = b2f((u16t)c8[e]);
    }
  }
  __syncthreads();
  const int d = t & 63, nl = t >> 6;
#pragma unroll
  for (int p = 0; p < 16; ++p) {
    const int n = p * 4 + nl;
    const long long idx = ((long long)b * 8192 + n0 + n) * 64 + d;
    const float s = states[idx];
    const float u = lu[d][n];
    const float c = lc[d][n];
    const float v = u * s + (1.f - u) * c;
    out[idx] = v;
    out[idx + 8388608] = v;
  }
}

extern "C" void kernel_launch(void* const* d_in, const int* in_sizes, int n_in,
                              void* d_out, int out_size, void* d_ws, size_t ws_size,
                              hipStream_t stream) {
  (void)in_sizes; (void)n_in; (void)out_size; (void)ws_size;
  const float* inputs   = (const float*)d_in[0];
  const float* states   = (const float*)d_in[1];
  const float* supports = (const float*)d_in[2];
  const float* Wru      = (const float*)d_in[3];
  const float* bru      = (const float*)d_in[4];
  const float* Wc       = (const float*)d_in[5];
  const float* bc       = (const float*)d_in[6];
  u16t* ws = (u16t*)d_ws;
  float* out = (float*)d_out;

  convert_s<<<65536, 256, 0, stream>>>(supports, ws);
  build_xt<<<dim3(128, 2, 16), 256, 0, stream>>>(inputs, states, ws);
  prep_w<<<480, 256, 0, stream>>>(Wru, Wc, ws);

  // gconv1: co-launch independent S0/S1 chains via blockIdx.z
  gemm256<<<dim3(32, 8, 2), 512, 0, stream>>>(ws + OFF_XT,  ws + OFF_S0, ws + OFF_X10,
                                              ws + OFF_XT,  ws + OFF_S1, ws + OFF_X11);
  gemm256<<<dim3(32, 8, 2), 512, 0, stream>>>(ws + OFF_X10, ws + OFF_S0, ws + OFF_Z0,
                                              ws + OFF_X11, ws + OFF_S1, ws + OFF_Z1);

  proj<<<dim3(64, 16), 256, 0, stream>>>(ws, ws, bru, 0);
  build_y<<<4096, 256, 0, stream>>>(ws);

  // gconv2 (1024 rows): co-launch restores full-chip occupancy
  gemm256<<<dim3(32, 4, 2), 512, 0, stream>>>(ws + OFF_YT,  ws + OFF_S0, ws + OFF_Y10,
                                              ws + OFF_YT,  ws + OFF_S1, ws + OFF_Y11);
  gemm256<<<dim3(32, 4, 2), 512, 0, stream>>>(ws + OFF_Y10, ws + OFF_S0, ws + OFF_ZY0,
                                              ws + OFF_Y11, ws + OFF_S1, ws + OFF_ZY1);

  proj<<<dim3(64, 16), 256, 0, stream>>>(ws, ws, bc, 1);
  final_out<<<dim3(128, 16), 256, 0, stream>>>(ws, states, out);
}

// Round 3
// 2313.246 us; speedup vs baseline: 1.1668x; 1.1668x over previous
//
#include <hip/hip_runtime.h>
#include <math.h>

typedef unsigned short u16t;
typedef unsigned int   u32t;
using short8 = __attribute__((ext_vector_type(8))) short;
using f32x4  = __attribute__((ext_vector_type(4))) float;

// ---------------- workspace layout (u16 elements) ----------------
#define SZ_S   67108864LL   // 8192*8192
#define SZ_F   16777216LL   // 2048*8192
#define SZ_G   8388608LL    // 1024*8192
#define OFF_S0  0LL
#define OFF_S1  67108864LL
#define OFF_XT  134217728LL  // x^T        (2048 x 8192) rows b*128 + dcat
#define OFF_X10 150994944LL  // (S0 x)^T
#define OFF_Z0  167772160LL  // (S0 S0 x)^T
#define OFF_X11 184549376LL  // (S1 x)^T
#define OFF_Z1  201326592LL  // (S1 S1 x)^T
#define OFF_RUT 218103808LL  // sigmoid(gconv1)^T (2048 x 8192) rows b*128 + o
#define OFF_YT  234881024LL  // (r*states)^T (1024 x 8192) rows b*64 + d
#define OFF_Y10 243269632LL
#define OFF_ZY0 251658240LL
#define OFF_Y11 260046848LL
#define OFF_ZY1 268435456LL
#define OFF_CT  276824064LL  // tanh(gconv2)^T (1024 x 8192)
#define OFF_WRU 285212672LL  // folded W_ru^T (128 x 640)
#define OFF_WC  285294592LL  // folded W_c^T  (64 x 640, padded to 128 rows)

__device__ __forceinline__ u16t f2b(float f) {   // fp32 -> bf16 RNE
  u32t x = __float_as_uint(f);
  x += 0x7fffu + ((x >> 16) & 1u);
  return (u16t)(x >> 16);
}
__device__ __forceinline__ float b2f(u16t h) {
  return __uint_as_float(((u32t)h) << 16);
}
__device__ __forceinline__ void async16(const u16t* g, u16t* l) {
  __builtin_amdgcn_global_load_lds((const __attribute__((address_space(1))) void*)g,
                                   (__attribute__((address_space(3))) void*)l, 16, 0, 0);
}

// ---------------- S fp32 -> bf16 (both supports, contiguous) ----------------
__global__ void convert_s(const float* __restrict__ S, u16t* __restrict__ ws) {
  const long long tid = (long long)blockIdx.x * 256 + threadIdx.x; // 16777216 threads
  const float4* p = (const float4*)S;
  const float4 a = p[tid * 2];
  const float4 b = p[tid * 2 + 1];
  short8 o;
  o[0] = (short)f2b(a.x); o[1] = (short)f2b(a.y);
  o[2] = (short)f2b(a.z); o[3] = (short)f2b(a.w);
  o[4] = (short)f2b(b.x); o[5] = (short)f2b(b.y);
  o[6] = (short)f2b(b.z); o[7] = (short)f2b(b.w);
  *(short8*)&ws[OFF_S0 + tid * 8] = o;
}

// ---------------- build x^T (2048 x 8192) bf16 from inputs/states ----------------
__global__ void build_xt(const float* __restrict__ inputs,
                         const float* __restrict__ states,
                         u16t* __restrict__ ws) {
  __shared__ float tile[64][65];
  const int n0 = blockIdx.x * 64;
  const int half = blockIdx.y;   // 0: inputs, 1: states
  const int b = blockIdx.z;
  const float* src = half ? states : inputs;
  const int t = threadIdx.x;
  const int d = t & 63, nl = t >> 6;
#pragma unroll
  for (int p = 0; p < 16; ++p) {
    const int n = p * 4 + nl;
    tile[d][n] = src[((long long)b * 8192 + n0 + n) * 64 + d];  // coalesced in d
  }
  __syncthreads();
  const int nn = t & 63, cl = t >> 6;
#pragma unroll
  for (int p = 0; p < 16; ++p) {
    const int c = p * 4 + cl;
    ws[OFF_XT + (long long)(b * 128 + half * 64 + c) * 8192 + n0 + nn] = f2b(tile[c][nn]);
  }
}

// ---------------- fold + transpose weights to bf16 ----------------
__global__ void prep_w(const float* __restrict__ Wru, const float* __restrict__ Wc,
                       u16t* __restrict__ ws) {
  const int t = blockIdx.x * 256 + threadIdx.x; // 122880 total
  if (t < 81920) {
    const int o = t / 640, f = t - o * 640;
    const int feat = f >> 7, dc = f & 127;
    float v;
    switch (feat) {
      case 0:  v = Wru[dc * 128 + o] - Wru[(256 + dc) * 128 + o] - Wru[(512 + dc) * 128 + o]; break;
      case 1:  v = Wru[(128 + dc) * 128 + o]; break;
      case 2:  v = 2.f * Wru[(256 + dc) * 128 + o]; break;
      case 3:  v = Wru[(384 + dc) * 128 + o]; break;
      default: v = 2.f * Wru[(512 + dc) * 128 + o]; break;
    }
    ws[OFF_WRU + t] = f2b(v);
  } else {
    const int t2 = t - 81920;
    const int o = t2 / 640, f = t2 - o * 640;
    const int feat = f >> 7, dc = f & 127;
    float v;
    switch (feat) {
      case 0:  v = Wc[dc * 64 + o] - Wc[(256 + dc) * 64 + o] - Wc[(512 + dc) * 64 + o]; break;
      case 1:  v = Wc[(128 + dc) * 64 + o]; break;
      case 2:  v = 2.f * Wc[(256 + dc) * 64 + o]; break;
      case 3:  v = Wc[(384 + dc) * 64 + o]; break;
      default: v = 2.f * Wc[(512 + dc) * 64 + o]; break;
    }
    ws[OFF_WC + t2] = f2b(v);
  }
}

// ---------------- big GEMM: 256x256 tile, BK=64, 8-phase, dbuf-2 ----------------
// Round-1 verified structure (stage placement + vmcnt(6) ledger identical).
// Change: ds_reads rebalanced {12,8,4,0} across the 4 phases so the LDS pipe
// runs evenly and each lgkm drain overlaps a prior MFMA cluster.
// Overwrite safety: af0 drained by ph1 lgkm0 (before ph2's A0 stage); af1
// drained by end-of-ph2 lgkm0 (before ph3's A1 stage); bf0 consumed by ph2
// MFMA (2 barriers before ph4's B0 stage); bf1 drained by ph3 lgkm0 (before
// T+1 ph1's B1 stage).
#define STAGE(g, lb, kt, half)                                                   \
  { const long long kk2 = (long long)(((kt) & 127) * 64);                        \
    async16((g) + ((long long)((half) * 128 + srl)) * 8192 + kk2 + ssx,          \
            (lb) + (half) * 8192 + sld);                                         \
    async16((g) + ((long long)((half) * 128 + srl + 8)) * 8192 + kk2 + ssx,      \
            (lb) + (half) * 8192 + sld + 512); }

#define GRP(T, CUR)                                                              \
  {                                                                              \
    short8 af0[8], af1[8], bf0[4], bf1[4];                                       \
    /* ---- phase 1: read af0+bf0 (12); stage B-half1 of T+1 ---- */             \
    _Pragma("unroll") for (int mi = 0; mi < 8; ++mi)                             \
      af0[mi] = *(const short8*)&As[CUR][ar0 + mi * 1024];                       \
    _Pragma("unroll") for (int nj = 0; nj < 4; ++nj)                             \
      bf0[nj] = *(const short8*)&Bs[CUR][br0 + nj * 1024];                       \
    STAGE(gB, Bs[1 - (CUR)], (T) + 1, 1);                                        \
    __builtin_amdgcn_s_barrier();                                                \
    asm volatile("s_waitcnt lgkmcnt(0)" ::: "memory");                           \
    __builtin_amdgcn_sched_barrier(0);                                           \
    __builtin_amdgcn_s_setprio(1);                                               \
    _Pragma("unroll") for (int mi = 0; mi < 8; ++mi) {                           \
      acc[mi][0] = __builtin_amdgcn_mfma_f32_16x16x32_bf16(af0[mi], bf0[0], acc[mi][0], 0, 0, 0); \
      acc[mi][1] = __builtin_amdgcn_mfma_f32_16x16x32_bf16(af0[mi], bf0[1], acc[mi][1], 0, 0, 0); \
    }                                                                            \
    __builtin_amdgcn_s_setprio(0);                                               \
    __builtin_amdgcn_s_barrier();                                                \
    /* ---- phase 2: read af1 (8); stage A-half0 of T+2 ---- */                  \
    _Pragma("unroll") for (int mi = 0; mi < 8; ++mi)                             \
      af1[mi] = *(const short8*)&As[CUR][ar1 + mi * 1024];                       \
    STAGE(gA, As[CUR], (T) + 2, 0);                                              \
    __builtin_amdgcn_s_barrier();                                                \
    __builtin_amdgcn_s_setprio(1);                                               \
    _Pragma("unroll") for (int mi = 0; mi < 8; ++mi) {                           \
      acc[mi][2] = __builtin_amdgcn_mfma_f32_16x16x32_bf16(af0[mi], bf0[2], acc[mi][2], 0, 0, 0); \
      acc[mi][3] = __builtin_amdgcn_mfma_f32_16x16x32_bf16(af0[mi], bf0[3], acc[mi][3], 0, 0, 0); \
    }                                                                            \
    __builtin_amdgcn_s_setprio(0);                                               \
    asm volatile("s_waitcnt lgkmcnt(0)" ::: "memory");                           \
    __builtin_amdgcn_s_barrier();                                                \
    /* ---- phase 3: read bf1 (4); stage A-half1 of T+2 ---- */                  \
    _Pragma("unroll") for (int nj = 0; nj < 4; ++nj)                             \
      bf1[nj] = *(const short8*)&Bs[CUR][br1 + nj * 1024];                       \
    STAGE(gA, As[CUR], (T) + 2, 1);                                              \
    __builtin_amdgcn_s_barrier();                                                \
    asm volatile("s_waitcnt lgkmcnt(0)" ::: "memory");                           \
    __builtin_amdgcn_sched_barrier(0);                                           \
    __builtin_amdgcn_s_setprio(1);                                               \
    _Pragma("unroll") for (int mi = 0; mi < 8; ++mi) {                           \
      acc[mi][0] = __builtin_amdgcn_mfma_f32_16x16x32_bf16(af1[mi], bf1[0], acc[mi][0], 0, 0, 0); \
      acc[mi][1] = __builtin_amdgcn_mfma_f32_16x16x32_bf16(af1[mi], bf1[1], acc[mi][1], 0, 0, 0); \
    }                                                                            \
    __builtin_amdgcn_s_setprio(0);                                               \
    __builtin_amdgcn_s_barrier();                                                \
    /* ---- phase 4: stage B-half0 of T+2; counted vmcnt retires T+1 ---- */     \
    STAGE(gB, Bs[CUR], (T) + 2, 0);                                              \
    __builtin_amdgcn_s_barrier();                                                \
    __builtin_amdgcn_s_setprio(1);                                               \
    _Pragma("unroll") for (int mi = 0; mi < 8; ++mi) {                           \
      acc[mi][2] = __builtin_amdgcn_mfma_f32_16x16x32_bf16(af1[mi], bf1[2], acc[mi][2], 0, 0, 0); \
      acc[mi][3] = __builtin_amdgcn_mfma_f32_16x16x32_bf16(af1[mi], bf1[3], acc[mi][3], 0, 0, 0); \
    }                                                                            \
    __builtin_amdgcn_s_setprio(0);                                               \
    asm volatile("s_waitcnt vmcnt(6)" ::: "memory");                             \
    __builtin_amdgcn_s_barrier();                                                \
  }

__global__ __launch_bounds__(512, 2) void gemm256(const u16t* __restrict__ Aa,
                                                  const u16t* __restrict__ Sa,
                                                  u16t* __restrict__ Oa,
                                                  const u16t* __restrict__ Ab,
                                                  const u16t* __restrict__ Sb,
                                                  u16t* __restrict__ Ob) {
  __shared__ __align__(16) u16t As[2][16384];   // [buf][256 rows][64 k]
  __shared__ __align__(16) u16t Bs[2][16384];
  const int t = threadIdx.x;
  const int l = t & 63;
  const int w = t >> 6;                 // 0..7
  // bijective XCD swizzle within the z-slice (nflat % 8 == 0 always here)
  const int id = blockIdx.y * 32 + blockIdx.x;
  const int cpx = (gridDim.y * 32) >> 3;
  const int swz = (id & 7) * cpx + (id >> 3);
  const int bx = swz & 31, by = swz >> 5;
  const long long m0 = (long long)bx * 256;
  const long long r0 = (long long)by * 256;
  const u16t* A = blockIdx.z ? Ab : Aa;
  const u16t* S = blockIdx.z ? Sb : Sa;
  u16t* Out = blockIdx.z ? Ob : Oa;
  const u16t* gA = A + r0 * 8192;
  const u16t* gB = S + m0 * 8192;

  const int wr = (w >> 2) * 128;        // A-row group: 0 or 128
  const int wc = (w & 3) * 64;          // B-row group: 0,64,128,192
  const int lm = l & 15, lq = l >> 4;

  // staging constants: seg = w*2+i covers rows seg*8..+7, lane l -> row +l>>3,
  // chunk (l&7) XOR-swizzled by row&7 == (l>>3)&7
  const int srl = w * 16 + (l >> 3);
  const int ssx = ((l & 7) ^ ((l >> 3) & 7)) * 8;
  const int sld = w * 1024 + l * 8;

  // fragment-read base offsets: row&7 == lm&7 (bases all 0 mod 8/16)
  const int ar0 = (wr + lm) * 64 + ((lq ^ (lm & 7)) * 8);
  const int ar1 = (wr + lm) * 64 + (((4 + lq) ^ (lm & 7)) * 8);
  const int br0 = (wc + lm) * 64 + ((lq ^ (lm & 7)) * 8);
  const int br1 = (wc + lm) * 64 + (((4 + lq) ^ (lm & 7)) * 8);

  f32x4 acc[8][4];
#pragma unroll
  for (int i = 0; i < 8; ++i)
#pragma unroll
    for (int j = 0; j < 4; ++j) acc[i][j] = f32x4{0.f, 0.f, 0.f, 0.f};

  // prologue: K-tile 0 fully, then 3 halves of K-tile 1 (stay in flight)
  STAGE(gA, As[0], 0, 0); STAGE(gA, As[0], 0, 1);
  STAGE(gB, Bs[0], 0, 0); STAGE(gB, Bs[0], 0, 1);
  asm volatile("s_waitcnt vmcnt(4)" ::: "memory");
  STAGE(gA, As[1], 1, 0); STAGE(gA, As[1], 1, 1);
  STAGE(gB, Bs[1], 1, 0);
  asm volatile("s_waitcnt vmcnt(6)" ::: "memory");
  __builtin_amdgcn_s_barrier();

#pragma unroll 1
  for (int T = 0; T < 128; T += 2) {
    GRP(T, 0)
    GRP(T + 1, 1)
  }

  // C/D layout: col = lane&15, row = (lane>>4)*4 + reg  [m89-verified]
#pragma unroll
  for (int mi = 0; mi < 8; ++mi)
#pragma unroll
    for (int nj = 0; nj < 4; ++nj)
#pragma unroll
      for (int rr = 0; rr < 4; ++rr) {
        const long long r = r0 + wr + mi * 16 + lq * 4 + rr;
        const long long c = m0 + wc + nj * 16 + lm;
        Out[r * 8192 + c] = f2b(acc[mi][nj][rr]);
      }
}

// ---------------- projection GEMM: K=640 over 10 chunk sources ----------------
// B-fragments loaded DIRECT global->VGPR (coalesced ushort rows, L3-resident;
// per-block n-slices are disjoint so traffic is unchanged). This removes the
// old Bt LDS scatter whose stride-72 layout was a 16-way bank conflict.
__global__ __launch_bounds__(256, 2) void proj(const u16t* __restrict__ ws_c,
                                               u16t* __restrict__ ws_m,
                                               const float* __restrict__ bias,
                                               const int variant) {
  __shared__ __align__(16) u16t As[128 * 64];
  const long long FOFF[5] = {OFF_XT, OFF_X10, OFF_Z0, OFF_X11, OFF_Z1};
  const long long GOFF[5] = {OFF_YT, OFF_Y10, OFF_ZY0, OFF_Y11, OFF_ZY1};
  const int t = threadIdx.x;
  const int l = t & 63;
  const int w = t >> 6;
  const int n0 = blockIdx.x * 128;
  const int b = blockIdx.y;
  const u16t* Wt = ws_c + (variant ? OFF_WC : OFF_WRU);

  const int srow = t >> 3;
  const int schunk = ((t & 7) ^ (srow & 7)) * 8;
  const int wr = (w >> 1) * 64, wm = (w & 1) * 64;
  const int lm = l & 15, lq = l >> 4;

  f32x4 acc[4][4];
#pragma unroll
  for (int i = 0; i < 4; ++i)
#pragma unroll
    for (int j = 0; j < 4; ++j) acc[i][j] = f32x4{0.f, 0.f, 0.f, 0.f};

  for (int q = 0; q < 10; ++q) {
    const int feat = q >> 1, half = q & 1;
    long long brow;
    if (variant == 0)
      brow = FOFF[feat] + (long long)(b * 128 + half * 64) * 8192;
    else
      brow = half ? (GOFF[feat] + (long long)(b * 64) * 8192)
                  : (FOFF[feat] + (long long)(b * 128) * 8192);
    // stage A (weights, K-contig) via swizzled global_load_lds
#pragma unroll
    for (int i = 0; i < 4; ++i)
      async16(Wt + (i * 32 + srow) * 640 + q * 64 + schunk, &As[i * 2048 + t * 8]);
    // B fragments direct to registers: lane (lm,lq) of n-tile j holds
    // B[n = n0+wm+j*16+lm][k = s*32+lq*8+e]
    short8 bq[2][4];
    const u16t* bp = ws_c + brow + (long long)(lq * 8) * 8192 + n0 + wm + lm;
#pragma unroll
    for (int s = 0; s < 2; ++s)
#pragma unroll
      for (int e = 0; e < 8; ++e) {
        const u16t* rp = bp + (long long)(s * 32 + e) * 8192;
        bq[s][0][e] = (short)rp[0];
        bq[s][1][e] = (short)rp[16];
        bq[s][2][e] = (short)rp[32];
        bq[s][3][e] = (short)rp[48];
      }
    __syncthreads();   // drains A-stage (vmcnt) + protects As from prev-q reads
#pragma unroll
    for (int s = 0; s < 2; ++s) {
      short8 af[4];
      const int ch = s * 4 + lq;
#pragma unroll
      for (int i = 0; i < 4; ++i) {
        const int mr = wr + i * 16 + lm;
        af[i] = *(const short8*)&As[mr * 64 + ((ch ^ (mr & 7)) * 8)];
      }
#pragma unroll
      for (int i = 0; i < 4; ++i)
#pragma unroll
        for (int j = 0; j < 4; ++j)
          acc[i][j] = __builtin_amdgcn_mfma_f32_16x16x32_bf16(af[i], bq[s][j], acc[i][j], 0, 0, 0);
    }
    __syncthreads();
  }

  if (variant == 0) {
#pragma unroll
    for (int i = 0; i < 4; ++i)
#pragma unroll
      for (int j = 0; j < 4; ++j)
#pragma unroll
        for (int rr = 0; rr < 4; ++rr) {
          const int o = wr + i * 16 + lq * 4 + rr;
          const int c = n0 + wm + j * 16 + lm;
          const float x = acc[i][j][rr] + bias[o];
          const float sg = 1.f / (1.f + __expf(-x));
          ws_m[OFF_RUT + (long long)(b * 128 + o) * 8192 + c] = f2b(sg);
        }
  } else if (wr == 0) {
#pragma unroll
    for (int i = 0; i < 4; ++i)
#pragma unroll
      for (int j = 0; j < 4; ++j)
#pragma unroll
        for (int rr = 0; rr < 4; ++rr) {
          const int o = i * 16 + lq * 4 + rr;  // < 64
          const int c = n0 + wm + j * 16 + lm;
          const float x = acc[i][j][rr] + bias[o];
          ws_m[OFF_CT + (long long)(b * 64 + o) * 8192 + c] = f2b(tanhf(x));
        }
  }
}

// ---------------- Y^T = (r * states)^T, bf16 ----------------
__global__ void build_y(u16t* __restrict__ ws) {
  const long long tid = (long long)blockIdx.x * 256 + threadIdx.x; // 1048576
  const int ry = (int)(tid >> 10);
  const int nc = ((int)tid & 1023) * 8;
  const int b = ry >> 6, d = ry & 63;
  const short8 r8 = *(const short8*)&ws[OFF_RUT + (long long)(b * 128 + d) * 8192 + nc];
  const short8 s8 = *(const short8*)&ws[OFF_XT + (long long)(b * 128 + 64 + d) * 8192 + nc];
  short8 o;
#pragma unroll
  for (int e = 0; e < 8; ++e) o[e] = (short)f2b(b2f((u16t)r8[e]) * b2f((u16t)s8[e]));
  *(short8*)&ws[OFF_YT + (long long)ry * 8192 + nc] = o;
}

// ---------------- final: out = u*states + (1-u)*c, two copies ----------------
__global__ void final_out(const u16t* __restrict__ ws,
                          const float* __restrict__ states,
                          float* __restrict__ out) {
  __shared__ float lu[64][65];
  __shared__ float lc[64][65];
  const int t = threadIdx.x;
  const int b = blockIdx.y;
  const int n0 = blockIdx.x * 64;
  const int dd = t >> 3, noff = (t & 7) * 8;
#pragma unroll
  for (int p = 0; p < 2; ++p) {
    const int d = p * 32 + dd;
    short8 u8 = *(const short8*)&ws[OFF_RUT + (long long)(b * 128 + 64 + d) * 8192 + n0 + noff];
    short8 c8 = *(const short8*)&ws[OFF_CT + (long long)(b * 64 + d) * 8192 + n0 + noff];
#pragma unroll
    for (int e = 0; e < 8; ++e) {
      lu[d][noff + e] = b2f((u16t)u8[e]);
      lc[d][noff + e] = b2f((u16t)c8[e]);
    }
  }
  __syncthreads();
  const int d = t & 63, nl = t >> 6;
#pragma unroll
  for (int p = 0; p < 16; ++p) {
    const int n = p * 4 + nl;
    const long long idx = ((long long)b * 8192 + n0 + n) * 64 + d;
    const float s = states[idx];
    const float u = lu[d][n];
    const float c = lc[d][n];
    const float v = u * s + (1.f - u) * c;
    out[idx] = v;
    out[idx + 8388608] = v;
  }
}

extern "C" void kernel_launch(void* const* d_in, const int* in_sizes, int n_in,
                              void* d_out, int out_size, void* d_ws, size_t ws_size,
                              hipStream_t stream) {
  (void)in_sizes; (void)n_in; (void)out_size; (void)ws_size;
  const float* inputs   = (const float*)d_in[0];
  const float* states   = (const float*)d_in[1];
  const float* supports = (const float*)d_in[2];
  const float* Wru      = (const float*)d_in[3];
  const float* bru      = (const float*)d_in[4];
  const float* Wc       = (const float*)d_in[5];
  const float* bc       = (const float*)d_in[6];
  u16t* ws = (u16t*)d_ws;
  float* out = (float*)d_out;

  convert_s<<<65536, 256, 0, stream>>>(supports, ws);
  build_xt<<<dim3(128, 2, 16), 256, 0, stream>>>(inputs, states, ws);
  prep_w<<<480, 256, 0, stream>>>(Wru, Wc, ws);

  // gconv1: co-launch independent S0/S1 chains via blockIdx.z
  gemm256<<<dim3(32, 8, 2), 512, 0, stream>>>(ws + OFF_XT,  ws + OFF_S0, ws + OFF_X10,
                                              ws + OFF_XT,  ws + OFF_S1, ws + OFF_X11);
  gemm256<<<dim3(32, 8, 2), 512, 0, stream>>>(ws + OFF_X10, ws + OFF_S0, ws + OFF_Z0,
                                              ws + OFF_X11, ws + OFF_S1, ws + OFF_Z1);

  proj<<<dim3(64, 16), 256, 0, stream>>>(ws, ws, bru, 0);
  build_y<<<4096, 256, 0, stream>>>(ws);

  // gconv2 (1024 rows): co-launch restores full-chip occupancy
  gemm256<<<dim3(32, 4, 2), 512, 0, stream>>>(ws + OFF_YT,  ws + OFF_S0, ws + OFF_Y10,
                                              ws + OFF_YT,  ws + OFF_S1, ws + OFF_Y11);
  gemm256<<<dim3(32, 4, 2), 512, 0, stream>>>(ws + OFF_Y10, ws + OFF_S0, ws + OFF_ZY0,
                                              ws + OFF_Y11, ws + OFF_S1, ws + OFF_ZY1);

  proj<<<dim3(64, 16), 256, 0, stream>>>(ws, ws, bc, 1);
  final_out<<<dim3(128, 16), 256, 0, stream>>>(ws, states, out);
}